// Round 7
// baseline (340.063 us; speedup 1.0000x reference)
//
#include <hip/hip_runtime.h>
#include <cmath>

#define NTOK 1024
#define NH 8
#define DH 64
#define BATCH 4
#define TBL 3969  // 63*63

#define L2E 1.4426950408889634f

typedef __attribute__((ext_vector_type(8))) short short8;
typedef __attribute__((ext_vector_type(4))) float f32x4;

__device__ __forceinline__ unsigned bf16rne(float x) {
  unsigned u = __float_as_uint(x);
  return (u + 0x7fffu + ((u >> 16) & 1u)) >> 16;
}

// pack 2 f32 -> 2 bf16 (RNE) hi parts + residual lo parts, 1 instr each pack
__device__ __forceinline__ void cvt2(float a, float b, unsigned& h, unsigned& l) {
  asm("v_cvt_pk_bf16_f32 %0, %1, %2" : "=v"(h) : "v"(a), "v"(b));
  float ra = a - __uint_as_float(h << 16);
  float rb = b - __uint_as_float(h & 0xffff0000u);
  asm("v_cvt_pk_bf16_f32 %0, %1, %2" : "=v"(l) : "v"(ra), "v"(rb));
}

__device__ __forceinline__ void split8_pk(const float* v, short8& h8, short8& l8) {
  union { short8 s; unsigned u[4]; } H, L;
#pragma unroll
  for (int j = 0; j < 4; ++j) {
    unsigned hp, lp;
    cvt2(v[2 * j], v[2 * j + 1], hp, lp);
    H.u[j] = hp; L.u[j] = lp;
  }
  h8 = H.s; l8 = L.s;
}

__device__ __forceinline__ f32x4 mfma16(short8 a, short8 b, f32x4 c) {
  return __builtin_amdgcn_mfma_f32_16x16x32_bf16(a, b, c, 0, 0, 0);
}

// global->LDS direct copy, 16B per lane (wave-uniform LDS base + lane*16)
__device__ __forceinline__ void gload16(const unsigned short* g, unsigned short* l) {
  __builtin_amdgcn_global_load_lds(
      (__attribute__((address_space(1))) unsigned int*)(g),
      (__attribute__((address_space(3))) unsigned int*)(l), 16, 0, 0);
}

// ---------------- Kernel 0: prep (x/W convert+transpose) + comb table ----------
// blocks [0,1024): x [4096][512] -> xh/xl linear bf16 split
// blocks [1024,1216): W_qkv [512][1536] -> wth/wtl [1536][512]
// blocks [1216,1280): W_out [512][512] -> wouth/woutl [512][512]
// blocks [1280,1296): combined RPE table (log2 domain)
__global__ __launch_bounds__(256) void k_prep(
    const float* __restrict__ x, const float* __restrict__ wqkv,
    const float* __restrict__ wout,
    unsigned short* __restrict__ xh, unsigned short* __restrict__ xl,
    unsigned short* __restrict__ wth, unsigned short* __restrict__ wtl,
    unsigned short* __restrict__ wouth, unsigned short* __restrict__ woutl,
    const float* __restrict__ t1, const float* __restrict__ t2,
    const float* __restrict__ sita, const float* __restrict__ dis,
    float* __restrict__ comb, float* __restrict__ combe) {
  const int bid = blockIdx.x;
  const int t = threadIdx.x;
  if (bid >= 1280) {
    int idx = (bid - 1280) * 256 + t;
    if (idx >= TBL) return;
    int dy = idx / 63 - 31, dx = idx % 63 - 31;
    int yi = dy > 0 ? dy : 0, yj = dy > 0 ? 0 : -dy;
    int xi = dx > 0 ? dx : 0, xj = dx > 0 ? 0 : -dx;
    float dv = dis[(size_t)(yi * 32 + xi) * NTOK + (yj * 32 + xj)];
#pragma unroll
    for (int h = 0; h < NH; ++h) {
      float ita = sita[h];
      float factor = 1.0f / (2.0f * ita * ita + 1e-6f);
      float bi = t1[idx * 8 + h] * t2[idx * 8 + h];
      float v = bi + 0.01f * expf(-factor * dv);
      comb[(size_t)h * TBL + idx] = v * L2E;
      combe[(size_t)h * TBL + idx] = expf(v);
    }
    return;
  }
  if (bid < 1024) {
    size_t base = ((size_t)bid * 256 + t) * 8;
    float v8[8];
    *(float4*)(v8) = *(const float4*)(x + base);
    *(float4*)(v8 + 4) = *(const float4*)(x + base + 4);
    short8 h8, l8;
    split8_pk(v8, h8, l8);
    *(short8*)(xh + base) = h8;
    *(short8*)(xl + base) = l8;
    return;
  }
  __shared__ float tile[64][65];
  const float* src;
  unsigned short *dh, *dl;
  int n0, k0, N;
  if (bid < 1216) {
    int b2 = bid - 1024;
    n0 = (b2 % 24) * 64; k0 = (b2 / 24) * 64; N = 1536;
    src = wqkv; dh = wth; dl = wtl;
  } else {
    int b2 = bid - 1216;
    n0 = (b2 % 8) * 64; k0 = (b2 / 8) * 64; N = 512;
    src = wout; dh = wouth; dl = woutl;
  }
#pragma unroll
  for (int l = 0; l < 4; ++l) {
    int idx = t + l * 256;
    int r = idx >> 4, c4 = idx & 15;
    float4 v = *(const float4*)(src + (size_t)(k0 + r) * N + n0 + c4 * 4);
    tile[r][c4 * 4 + 0] = v.x; tile[r][c4 * 4 + 1] = v.y;
    tile[r][c4 * 4 + 2] = v.z; tile[r][c4 * 4 + 3] = v.w;
  }
  __syncthreads();
#pragma unroll
  for (int l = 0; l < 2; ++l) {
    int idx = t + l * 256;
    int n = idx >> 3, c8 = idx & 7;
    float v8[8];
#pragma unroll
    for (int j = 0; j < 8; ++j) v8[j] = tile[c8 * 8 + j][n];
    short8 h8, l8;
    split8_pk(v8, h8, l8);
    *(short8*)(dh + (size_t)(n0 + n) * 512 + k0 + c8 * 8) = h8;
    *(short8*)(dl + (size_t)(n0 + n) * 512 + k0 + c8 * 8) = l8;
  }
}

// ---------------- shared MFMA GEMM core (split-bf16, AR x BR tile, K=512) ------
// A,B stored [row][512] bf16 row-major (hi/lo arrays). Stages ARx64 + BRx64
// tiles via global_load_lds, XOR-swizzled (16B unit u at row r -> u^(r&7)).
// 4 waves: wr = w>>1 owns M-half (AR/2), wc = w&1 owns N-half (BR/2).
// acc[mt][nt]: D[m = (AR/2)wr+16mt+4q+j][n = (BR/2)wc+16nt+li].
template <int AR, int BR>
__device__ __forceinline__ void gemm_core(
    const unsigned short* __restrict__ pAh, const unsigned short* __restrict__ pAl,
    const unsigned short* __restrict__ pBh, const unsigned short* __restrict__ pBl,
    int a0, int b0, int t, f32x4 acc[AR / 32][BR / 32],
    unsigned short* AhS, unsigned short* AlS,
    unsigned short* BhS, unsigned short* BlS) {
  constexpr int MT = AR / 32, NT = BR / 32;
  const int lane = t & 63;
  const int w = t >> 6;
  const int q = lane >> 4, li = lane & 15;
  const int wr = w >> 1, wc = w & 1;
#pragma unroll 1
  for (int k0 = 0; k0 < 512; k0 += 64) {
#pragma unroll
    for (int l = 0; l < AR / 32; ++l) {
      int idx = l * 256 + t;
      int row = idx >> 3, u = idx & 7;
      int so = k0 + ((u ^ (row & 7)) * 8);
      gload16(pAh + (size_t)(a0 + row) * 512 + so, AhS + idx * 8);
      gload16(pAl + (size_t)(a0 + row) * 512 + so, AlS + idx * 8);
    }
#pragma unroll
    for (int l = 0; l < BR / 32; ++l) {
      int idx = l * 256 + t;
      int row = idx >> 3, u = idx & 7;
      int so = k0 + ((u ^ (row & 7)) * 8);
      gload16(pBh + (size_t)(b0 + row) * 512 + so, BhS + idx * 8);
      gload16(pBl + (size_t)(b0 + row) * 512 + so, BlS + idx * 8);
    }
    __syncthreads();
#pragma unroll
    for (int c = 0; c < 2; ++c) {
      short8 aH[MT], aL[MT], bH[NT], bL[NT];
#pragma unroll
      for (int mt = 0; mt < MT; ++mt) {
        int row = (AR / 2) * wr + 16 * mt + li;
        int ro = row * 64 + (((4 * c + q) ^ (row & 7)) * 8);
        aH[mt] = *(const short8*)(AhS + ro);
        aL[mt] = *(const short8*)(AlS + ro);
      }
#pragma unroll
      for (int nt = 0; nt < NT; ++nt) {
        int row = (BR / 2) * wc + 16 * nt + li;
        int ro = row * 64 + (((4 * c + q) ^ (row & 7)) * 8);
        bH[nt] = *(const short8*)(BhS + ro);
        bL[nt] = *(const short8*)(BlS + ro);
      }
#pragma unroll
      for (int mt = 0; mt < MT; ++mt)
#pragma unroll
        for (int nt = 0; nt < NT; ++nt) {
          acc[mt][nt] = mfma16(aH[mt], bH[nt], acc[mt][nt]);
          acc[mt][nt] = mfma16(aH[mt], bL[nt], acc[mt][nt]);
          acc[mt][nt] = mfma16(aL[mt], bH[nt], acc[mt][nt]);
        }
    }
    __syncthreads();
  }
}

// ---------------- Kernel 1: QKV GEMM — 768 blocks (3/CU), 64x128 tiles ---------
// bx = part*8 + h (24), by = 128-token tile (32). Q/K swapped (A=W^T 64 rows,
// B=x 128 rows): lane holds 4 consecutive d. V normal (A=x, B=W^T): lane holds
// 4 consecutive tokens for one d.
__global__ __launch_bounds__(256, 3) void k_qkv(
    const unsigned short* __restrict__ xh, const unsigned short* __restrict__ xl,
    const unsigned short* __restrict__ wth, const unsigned short* __restrict__ wtl,
    float* __restrict__ qf, unsigned short* __restrict__ kspl,
    unsigned short* __restrict__ vspl) {
  __shared__ unsigned short S[24576];  // 48 KB
  const int bid = blockIdx.x;                 // 0..767
  const int lin = (bid & 7) * 96 + (bid >> 3);
  const int by = lin / 24, bx = lin % 24;
  const int part = bx >> 3, h = bx & 7;
  const int t = threadIdx.x;
  const int lane = t & 63;
  const int w = t >> 6;
  const int q = lane >> 4, li = lane & 15;
  const int wr = w >> 1, wc = w & 1;

  if (part < 2) {
    f32x4 acc[2][4] = {};
    int a0 = part * 512 + h * 64;
    gemm_core<64, 128>(wth, wtl, xh, xl, a0, by * 128, t, acc,
                       S, S + 4096, S + 8192, S + 16384);
    if (part == 0) {
#pragma unroll
      for (int nt = 0; nt < 4; ++nt) {
        int tok = by * 128 + 64 * wc + 16 * nt + li;
        int b = tok >> 10, i = tok & 1023;
#pragma unroll
        for (int mt = 0; mt < 2; ++mt) {
          int d0 = 32 * wr + 16 * mt + 4 * q;
          float4 v;
          v.x = acc[mt][nt][0]; v.y = acc[mt][nt][1];
          v.z = acc[mt][nt][2]; v.w = acc[mt][nt][3];
          *(float4*)(qf + ((size_t)(b * NH + h) * NTOK + i) * DH + d0) = v;
        }
      }
    } else {
#pragma unroll
      for (int nt = 0; nt < 4; ++nt) {
        int tok = by * 128 + 64 * wc + 16 * nt + li;
        int b = tok >> 10, tile = (tok & 1023) >> 6, tl = tok & 63;
        unsigned short* kb = kspl + ((size_t)((b * NH + h) * 16 + tile) * 2) * 4096;
#pragma unroll
        for (int mt = 0; mt < 2; ++mt) {
          int d0 = 32 * wr + 16 * mt + 4 * q;
          int pu = (d0 >> 3) ^ (tl & 7), off = d0 & 7;
          unsigned h0, h1, l0, l1;
          cvt2(acc[mt][nt][0], acc[mt][nt][1], h0, l0);
          cvt2(acc[mt][nt][2], acc[mt][nt][3], h1, l1);
          *(uint2*)(kb + tl * 64 + pu * 8 + off) = make_uint2(h0, h1);
          *(uint2*)(kb + 4096 + tl * 64 + pu * 8 + off) = make_uint2(l0, l1);
        }
      }
    }
  } else {
    f32x4 acc[4][2] = {};
    gemm_core<128, 64>(xh, xl, wth, wtl, by * 128, 1024 + h * 64, t, acc,
                       S, S + 8192, S + 16384, S + 20480);
#pragma unroll
    for (int mt = 0; mt < 4; ++mt) {
      int tok0 = by * 128 + 64 * wr + 16 * mt + 4 * q;
      int b = tok0 >> 10, tile = (tok0 & 1023) >> 6, tl0 = tok0 & 63;
      int lu = tl0 >> 3, off = tl0 & 7;
      unsigned short* vb = vspl + ((size_t)((b * NH + h) * 16 + tile) * 2) * 4096;
#pragma unroll
      for (int nt = 0; nt < 2; ++nt) {
        int d = 32 * wc + 16 * nt + li;
        int pu = lu ^ (d & 7);
        unsigned h0, h1, l0, l1;
        cvt2(acc[mt][nt][0], acc[mt][nt][1], h0, l0);
        cvt2(acc[mt][nt][2], acc[mt][nt][3], h1, l1);
        *(uint2*)(vb + d * 64 + pu * 8 + off) = make_uint2(h0, h1);
        *(uint2*)(vb + 4096 + d * 64 + pu * 8 + off) = make_uint2(l0, l1);
      }
    }
  }
}

// ---------------- Kernel 2: fused attention, 8 waves, XCD-swizzled -------------
// attn0 emitted with direct PLAIN dword stores (L2 write-back merges 64B
// quarter-wave granules to full lines; NT scatter measured +45-57 MB HBM
// amplification, LDS-staged bulk copy measured +7 µs overhead).
// LDS 52 KB -> 3 blocks/CU; __launch_bounds__(512,6) requests 24 waves/CU.
__global__ __launch_bounds__(512, 6) void k_attn(
    const float* __restrict__ qf, const unsigned short* __restrict__ kspl,
    const unsigned short* __restrict__ vspl, const float* __restrict__ prob,
    const float* __restrict__ comb, const float* __restrict__ combe,
    const float* __restrict__ wt,
    float* __restrict__ attn0, unsigned short* __restrict__ oh,
    unsigned short* __restrict__ ol) {
  __shared__ unsigned short KhS[4096], KlS[4096];  // K [tok][d] bf16 hi/lo (swz)
  __shared__ unsigned short VhS[4096], VlS[4096];  // V^T [d][jj] bf16 hi/lo (swz)
  __shared__ float PfS[64 * 68];                   // P / merge scratch
  __shared__ float2 csS[3 * 64];                   // (comb*log2e, exp(comb))
  __shared__ float thrS[64];

  const int bid = blockIdx.x;
  const int lin = (bid & 7) * 64 + (bid >> 3);  // 16 row-tiles of a bh per XCD
  const int bh = lin >> 4;
  const int rt = lin & 15;
  const int b = bh >> 3, h = bh & 7;
  const int i0 = rt * 64;
  const int t = threadIdx.x;
  const int w = t >> 6;
  const int lane = t & 63;
  const int q = lane >> 4, li = lane & 15;
  const int g = w >> 1;                    // rows 16g..16g+15
  const int cw = w & 1;                    // column half
  const float* qb = qf + (size_t)bh * NTOK * DH;
  const float* ch = comb + (size_t)h * TBL;
  const float* che = combe + (size_t)h * TBL;
  const int rbase = (i0 >> 5) + 30;

  // thresh_raw = sigmoid(q . W_thresh) * sigmoid(-2)
  {
    int row = t >> 3, dg = t & 7;
    const float* qr2 = qb + (size_t)(i0 + row) * DH + dg * 8;
    float sum = 0.f;
#pragma unroll
    for (int c = 0; c < 8; ++c) sum += qr2[c] * wt[dg * 8 + c];
    sum += __shfl_xor(sum, 1);
    sum += __shfl_xor(sum, 2);
    sum += __shfl_xor(sum, 4);
    if (dg == 0)
      thrS[row] = (1.0f / (1.0f + exp2f(-sum * L2E))) * 0.11920292202211755f;
  }

  // Q fragments, prescaled by 0.125*log2e
  short8 qah[2], qal[2];
  {
    const float* qr2 = qb + (size_t)(i0 + 16 * g + li) * DH;
    const float QS = 0.125f * L2E;
#pragma unroll
    for (int c = 0; c < 2; ++c) {
      float4 a = *(const float4*)(qr2 + 32 * c + 8 * q);
      float4 bb = *(const float4*)(qr2 + 32 * c + 8 * q + 4);
      float tmp[8] = {a.x * QS, a.y * QS, a.z * QS, a.w * QS,
                      bb.x * QS, bb.y * QS, bb.z * QS, bb.w * QS};
      split8_pk(tmp, qah[c], qal[c]);
    }
  }

  float m0l[4], s0l[4], ml[4], sl[4], mnl[4];
#pragma unroll
  for (int r = 0; r < 4; ++r) {
    m0l[r] = -1e30f; ml[r] = -1e30f; mnl[r] = 1e30f;
    s0l[r] = 0.f; sl[r] = 0.f;
  }

  // ================= pass 1: stats =================
#pragma unroll 1
  for (int j0 = 0; j0 < NTOK; j0 += 64) {
    const unsigned short* gk = kspl + ((size_t)(bh * 16 + (j0 >> 6)) * 2) * 4096;
    gload16(gk + w * 512 + lane * 8, KhS + w * 512);
    gload16(gk + 4096 + w * 512 + lane * 8, KlS + w * 512);
    if (t < 192) {
      int rl2 = t >> 6, c2 = t & 63;
      if (c2 < 63) {
        int off = (rbase - (j0 >> 5) + rl2) * 63 + c2;
        csS[rl2 * 64 + c2] = make_float2(ch[off], che[off]);
      }
    }
    __syncthreads();

    f32x4 acc2[2] = {};
#pragma unroll
    for (int c = 0; c < 2; ++c) {
#pragma unroll
      for (int T2 = 0; T2 < 2; ++T2) {
        int T = 2 * cw + T2;
        int ro = (16 * T + li) * 64 + ((4 * c + q) ^ (li & 7)) * 8;
        short8 bh8 = *(const short8*)(KhS + ro);
        short8 bl8 = *(const short8*)(KlS + ro);
        acc2[T2] = mfma16(qah[c], bh8, acc2[T2]);
        acc2[T2] = mfma16(qah[c], bl8, acc2[T2]);
        acc2[T2] = mfma16(qal[c], bh8, acc2[T2]);
      }
    }

    float2 ce[2][4];
    float t0[4], tt[4], tmn[4];
#pragma unroll
    for (int r = 0; r < 4; ++r) { t0[r] = -1e30f; tt[r] = -1e30f; tmn[r] = 1e30f; }
#pragma unroll
    for (int T2 = 0; T2 < 2; ++T2) {
      int jj = 16 * (2 * cw + T2) + li;
      int rl2 = (g >> 1) - (jj >> 5) + 1;
      int cb = 16 * (g & 1) + 4 * q - (jj & 31) + 31;
      const float2* cp = csS + rl2 * 64 + cb;
#pragma unroll
      for (int r = 0; r < 4; ++r) {
        ce[T2][r] = cp[r];
        float d0 = acc2[T2][r];
        float dt = d0 + ce[T2][r].x;
        t0[r] = fmaxf(t0[r], d0);
        tt[r] = fmaxf(tt[r], dt);
        tmn[r] = fminf(tmn[r], dt);
      }
    }
#pragma unroll
    for (int r = 0; r < 4; ++r) {
      float nm0 = fmaxf(m0l[r], t0[r]);
      float nm = fmaxf(ml[r], tt[r]);
      float sc0 = exp2f(m0l[r] - nm0), sc = exp2f(ml[r] - nm), k0 = exp2f(nm0 - nm);
      float s0a = 0.f, sEa = 0.f;
#pragma unroll
      for (int T2 = 0; T2 < 2; ++T2) {
        float e0 = exp2f(acc2[T2][r] - nm0);
        s0a += e0;
        sEa += e0 * ce[T2][r].y;
      }
      s0l[r] = s0l[r] * sc0 + s0a;
      sl[r] = sl[r] * sc + sEa * k0;
      m0l[r] = nm0; ml[r] = nm; mnl[r] = fminf(mnl[r], tmn[r]);
    }
    __syncthreads();
  }

  // ========= finalize: intra-wave (li) reduce, cross-pair merge via LDS =======
  float M0[4], S0v[4], M[4], Sv[4], MN[4];
#pragma unroll
  for (int r = 0; r < 4; ++r) {
    float m0v = m0l[r], s0 = s0l[r], m = ml[r], s = sl[r], mn = mnl[r];
#pragma unroll
    for (int off = 1; off < 16; off <<= 1) {
      float om = __shfl_xor(m0v, off), os = __shfl_xor(s0, off);
      float n0 = fmaxf(m0v, om);
      s0 = s0 * exp2f(m0v - n0) + os * exp2f(om - n0);
      m0v = n0;
      float om2 = __shfl_xor(m, off), os2 = __shfl_xor(s, off);
      float n2 = fmaxf(m, om2);
      s = s * exp2f(m - n2) + os2 * exp2f(om2 - n2);
      m = n2;
      mn = fminf(mn, __shfl_xor(mn, off));
    }
    M0[r] = m0v; S0v[r] = s0; M[r] = m; Sv[r] = s; MN[r] = mn;
  }
  if (li == 0) {
#pragma unroll
    for (int r = 0; r < 4; ++r) {
      int row = 16 * g + 4 * q + r;
      float* p = PfS + (cw * 64 + row) * 5;
      p[0] = M0[r]; p[1] = S0v[r]; p[2] = M[r]; p[3] = Sv[r]; p[4] = MN[r];
    }
  }
  __syncthreads();

  float m0f[4], is0f[4], thf[4], crf[4];
#pragma unroll
  for (int r = 0; r < 4; ++r) {
    int rloc = 16 * g + 4 * q + r;
    const float* pa = PfS + rloc * 5;
    const float* pb = PfS + (64 + rloc) * 5;
    float m0v = fmaxf(pa[0], pb[0]);
    float s0 = pa[1] * exp2f(pa[0] - m0v) + pb[1] * exp2f(pb[0] - m0v);
    float m = fmaxf(pa[2], pb[2]);
    float s = pa[3] * exp2f(pa[2] - m) + pb[3] * exp2f(pb[2] - m);
    float mn = fminf(pa[4], pb[4]);
    float isf = 1.f / s;
    float amin = exp2f(mn - m) * isf;
    float th = amin + thrS[rloc] * (isf - amin);
    if (prob[b * NTOK + i0 + rloc] >= 0.9f) th = 1e30f;
    m0f[r] = m0v; is0f[r] = 1.f / s0; thf[r] = th; crf[r] = exp2f(m0v - m) * isf;
  }
  __syncthreads();  // scratch reads done before pass 2 overwrites PfS

  // ================= pass 2: attn0 (direct plain stores), P, PV =================
  f32x4 oacc[4] = {};
  float denl[4] = {0.f, 0.f, 0.f, 0.f};
#pragma unroll 1
  for (int j0 = 0; j0 < NTOK; j0 += 64) {
    const unsigned short* gk = kspl + ((size_t)(bh * 16 + (j0 >> 6)) * 2) * 4096;
    const unsigned short* gv = vspl + ((size_t)(bh * 16 + (j0 >> 6)) * 2) * 4096;
    gload16(gk + w * 512 + lane * 8, KhS + w * 512);
    gload16(gk + 4096 + w * 512 + lane * 8, KlS + w * 512);
    gload16(gv + w * 512 + lane * 8, VhS + w * 512);
    gload16(gv + 4096 + w * 512 + lane * 8, VlS + w * 512);
    if (t < 192) {
      int rl2 = t >> 6, c2 = t & 63;
      if (c2 < 63) {
        int off = (rbase - (j0 >> 5) + rl2) * 63 + c2;
        csS[rl2 * 64 + c2] = make_float2(ch[off], che[off]);
      }
    }
    __syncthreads();

    f32x4 acc2[2] = {};
#pragma unroll
    for (int c = 0; c < 2; ++c) {
#pragma unroll
      for (int T2 = 0; T2 < 2; ++T2) {
        int T = 2 * cw + T2;
        int ro = (16 * T + li) * 64 + ((4 * c + q) ^ (li & 7)) * 8;
        short8 bh8 = *(const short8*)(KhS + ro);
        short8 bl8 = *(const short8*)(KlS + ro);
        acc2[T2] = mfma16(qah[c], bh8, acc2[T2]);
        acc2[T2] = mfma16(qah[c], bl8, acc2[T2]);
        acc2[T2] = mfma16(qal[c], bh8, acc2[T2]);
      }
    }

#pragma unroll
    for (int T2 = 0; T2 < 2; ++T2) {
      int jj = 16 * (2 * cw + T2) + li;
      int rl2 = (g >> 1) - (jj >> 5) + 1;
      int cb = 16 * (g & 1) + 4 * q - (jj & 31) + 31;
      const float2* cp = csS + rl2 * 64 + cb;
      int il0 = 16 * g + 4 * q;
      float* a0p = attn0 + (size_t)(bh * NTOK + i0 + il0) * NTOK + j0 + jj;
#pragma unroll
      for (int r = 0; r < 4; ++r) {
        float ey = cp[r].y;
        float e0 = exp2f(acc2[T2][r] - m0f[r]);
        a0p[(size_t)r * NTOK] = e0 * is0f[r];   // plain store: L2 merges lines
        float at = e0 * ey * crf[r];
        float p = (at - thf[r] > 0.f) ? at : 0.f;
        denl[r] += p;
        PfS[(il0 + r) * 68 + jj] = p;
      }
    }
    // PV over this wave's 32 j-cols (wave-private P region), all 64 d
    {
      const float* pp = PfS + (16 * g + li) * 68 + 32 * cw + 8 * q;
      float pv8[8];
      *(float4*)(pv8) = *(const float4*)pp;
      *(float4*)(pv8 + 4) = *(const float4*)(pp + 4);
      short8 pah, pal;
      split8_pk(pv8, pah, pal);
#pragma unroll
      for (int T = 0; T < 4; ++T) {
        int ro = (16 * T + li) * 64 + ((4 * cw + q) ^ (li & 7)) * 8;
        short8 vh8 = *(const short8*)(VhS + ro);
        short8 vl8 = *(const short8*)(VlS + ro);
        oacc[T] = mfma16(pah, vh8, oacc[T]);
        oacc[T] = mfma16(pah, vl8, oacc[T]);
        oacc[T] = mfma16(pal, vh8, oacc[T]);
      }
    }
    __syncthreads();
  }

  // ========= epilogue: merge O + deno across wave pair, store split-bf16 ======
#pragma unroll
  for (int r = 0; r < 4; ++r) {
#pragma unroll
    for (int off = 1; off < 16; off <<= 1) denl[r] += __shfl_xor(denl[r], off);
  }
  if (cw == 1) {
#pragma unroll
    for (int r = 0; r < 4; ++r) {
      int row = 16 * g + 4 * q + r;
#pragma unroll
      for (int T = 0; T < 4; ++T) PfS[row * 68 + 16 * T + li] = oacc[T][r];
      if (li == 0) PfS[row * 68 + 64] = denl[r];
    }
  }
  __syncthreads();
  if (cw == 0) {
#pragma unroll
    for (int r = 0; r < 4; ++r) {
      int rloc = 16 * g + 4 * q + r;
      float dsum = denl[r] + PfS[rloc * 68 + 64];
      float pf = 1.f / (dsum + 1e-6f);
      int row = i0 + rloc;
      size_t rb2 = ((size_t)b * NTOK + row) * 512 + h * 64;
#pragma unroll
      for (int T = 0; T < 4; ++T) {
        float val = (oacc[T][r] + PfS[rloc * 68 + 16 * T + li]) * pf;
        unsigned hv = bf16rne(val);
        float lo2 = val - __uint_as_float(hv << 16);
        oh[rb2 + 16 * T + li] = (unsigned short)hv;
        ol[rb2 + 16 * T + li] = (unsigned short)bf16rne(lo2);
      }
    }
  }
}

// ---------------- Kernel 3: output GEMM — 256 blocks (1/CU), 64x128 tiles ------
__global__ __launch_bounds__(256, 3) void k_out(
    const unsigned short* __restrict__ wouth, const unsigned short* __restrict__ woutl,
    const unsigned short* __restrict__ oh, const unsigned short* __restrict__ ol,
    const float* __restrict__ bias, float* __restrict__ c) {
  __shared__ unsigned short S[24576];
  const int bid = blockIdx.x;                 // 0..255
  const int lin = (bid & 7) * 32 + (bid >> 3);
  const int by = lin >> 3, bx = lin & 7;
  const int t = threadIdx.x;
  const int lane = t & 63;
  const int w = t >> 6;
  const int q = lane >> 4, li = lane & 15;
  const int wr = w >> 1, wc = w & 1;
  f32x4 acc[2][4] = {};
  gemm_core<64, 128>(wouth, woutl, oh, ol, bx * 64, by * 128, t, acc,
                     S, S + 4096, S + 8192, S + 16384);
#pragma unroll
  for (int mt = 0; mt < 2; ++mt) {
    int col0 = bx * 64 + 32 * wr + 16 * mt + 4 * q;
    float4 b4 = *(const float4*)(bias + col0);
#pragma unroll
    for (int nt = 0; nt < 4; ++nt) {
      int tok = by * 128 + 64 * wc + 16 * nt + li;
      float4 v;
      v.x = acc[mt][nt][0] + b4.x; v.y = acc[mt][nt][1] + b4.y;
      v.z = acc[mt][nt][2] + b4.z; v.w = acc[mt][nt][3] + b4.w;
      *(float4*)(c + (size_t)tok * 512 + col0) = v;
    }
  }
}

extern "C" void kernel_launch(void* const* d_in, const int* in_sizes, int n_in,
                              void* d_out, int out_size, void* d_ws, size_t ws_size,
                              hipStream_t stream) {
  const float* x    = (const float*)d_in[0];
  const float* prob = (const float*)d_in[1];
  const float* wqkv = (const float*)d_in[2];
  const float* t1   = (const float*)d_in[3];
  const float* t2   = (const float*)d_in[4];
  const float* sita = (const float*)d_in[5];
  const float* wt   = (const float*)d_in[6];
  const float* wout = (const float*)d_in[7];
  const float* bout = (const float*)d_in[8];
  const float* dis  = (const float*)d_in[10];

  float* out = (float*)d_out;
  float* attn0 = out + (size_t)BATCH * NTOK * 512;

  float* comb = (float*)d_ws;                          // 32768 f (log2 domain)
  float* combe = comb + 32768;                         // 32768 f
  float* qf = combe + 32768;                           // 2,097,152 f (Q fp32)
  unsigned short* kspl = (unsigned short*)(qf + (size_t)BATCH * NH * NTOK * DH);  // 8 MB
  unsigned short* vspl = kspl + (size_t)4194304;                                  // 8 MB
  unsigned short* xh = vspl + (size_t)4194304;         // 4 MB (reused as oh)
  unsigned short* xl = xh + (size_t)2097152;           // 4 MB (reused as ol)
  unsigned short* wth = xl + (size_t)2097152;          // 1.5 MB
  unsigned short* wtl = wth + (size_t)786432;          // 1.5 MB
  unsigned short* wouth = wtl + (size_t)786432;        // 0.5 MB
  unsigned short* woutl = wouth + (size_t)262144;      // 0.5 MB
  unsigned short* oh = xh;  // alias: x consumed by k_qkv before k_attn writes o
  unsigned short* ol = xl;

  hipLaunchKernelGGL(k_prep, dim3(1296), dim3(256), 0, stream,
                     x, wqkv, wout, xh, xl, wth, wtl, wouth, woutl,
                     t1, t2, sita, dis, comb, combe);
  hipLaunchKernelGGL(k_qkv, dim3(768), dim3(256), 0, stream,
                     xh, xl, wth, wtl, qf, kspl, vspl);
  hipLaunchKernelGGL(k_attn, dim3(512), dim3(512), 0, stream,
                     qf, kspl, vspl, prob, comb, combe, wt, attn0, oh, ol);
  hipLaunchKernelGGL(k_out, dim3(256), dim3(256), 0, stream,
                     wouth, woutl, oh, ol, bout, out);
}

// Round 8
// 266.992 us; speedup vs baseline: 1.2737x; 1.2737x over previous
//
#include <hip/hip_runtime.h>
#include <cmath>

#define NTOK 1024
#define NH 8
#define DH 64
#define BATCH 4
#define TBL 3969  // 63*63

#define L2E 1.4426950408889634f

typedef __attribute__((ext_vector_type(8))) short short8;
typedef __attribute__((ext_vector_type(4))) float f32x4;

__device__ __forceinline__ unsigned bf16rne(float x) {
  unsigned u = __float_as_uint(x);
  return (u + 0x7fffu + ((u >> 16) & 1u)) >> 16;
}

// pack 2 f32 -> 2 bf16 (RNE) hi parts + residual lo parts, 1 instr each pack
__device__ __forceinline__ void cvt2(float a, float b, unsigned& h, unsigned& l) {
  asm("v_cvt_pk_bf16_f32 %0, %1, %2" : "=v"(h) : "v"(a), "v"(b));
  float ra = a - __uint_as_float(h << 16);
  float rb = b - __uint_as_float(h & 0xffff0000u);
  asm("v_cvt_pk_bf16_f32 %0, %1, %2" : "=v"(l) : "v"(ra), "v"(rb));
}

__device__ __forceinline__ void split8_pk(const float* v, short8& h8, short8& l8) {
  union { short8 s; unsigned u[4]; } H, L;
#pragma unroll
  for (int j = 0; j < 4; ++j) {
    unsigned hp, lp;
    cvt2(v[2 * j], v[2 * j + 1], hp, lp);
    H.u[j] = hp; L.u[j] = lp;
  }
  h8 = H.s; l8 = L.s;
}

__device__ __forceinline__ f32x4 mfma16(short8 a, short8 b, f32x4 c) {
  return __builtin_amdgcn_mfma_f32_16x16x32_bf16(a, b, c, 0, 0, 0);
}

// global->LDS direct copy, 16B per lane (wave-uniform LDS base + lane*16)
__device__ __forceinline__ void gload16(const unsigned short* g, unsigned short* l) {
  __builtin_amdgcn_global_load_lds(
      (__attribute__((address_space(1))) unsigned int*)(g),
      (__attribute__((address_space(3))) unsigned int*)(l), 16, 0, 0);
}

// ---------------- Kernel 0: prep (x/W convert+transpose) + comb table ----------
// blocks [0,1024): x [4096][512] -> xh/xl linear bf16 split
// blocks [1024,1216): W_qkv [512][1536] -> wth/wtl [1536][512]
// blocks [1216,1280): W_out [512][512] -> wouth/woutl [512][512]
// blocks [1280,1296): combined RPE table (log2 domain)
__global__ __launch_bounds__(256) void k_prep(
    const float* __restrict__ x, const float* __restrict__ wqkv,
    const float* __restrict__ wout,
    unsigned short* __restrict__ xh, unsigned short* __restrict__ xl,
    unsigned short* __restrict__ wth, unsigned short* __restrict__ wtl,
    unsigned short* __restrict__ wouth, unsigned short* __restrict__ woutl,
    const float* __restrict__ t1, const float* __restrict__ t2,
    const float* __restrict__ sita, const float* __restrict__ dis,
    float* __restrict__ comb, float* __restrict__ combe) {
  const int bid = blockIdx.x;
  const int t = threadIdx.x;
  if (bid >= 1280) {
    int idx = (bid - 1280) * 256 + t;
    if (idx >= TBL) return;
    int dy = idx / 63 - 31, dx = idx % 63 - 31;
    int yi = dy > 0 ? dy : 0, yj = dy > 0 ? 0 : -dy;
    int xi = dx > 0 ? dx : 0, xj = dx > 0 ? 0 : -dx;
    float dv = dis[(size_t)(yi * 32 + xi) * NTOK + (yj * 32 + xj)];
#pragma unroll
    for (int h = 0; h < NH; ++h) {
      float ita = sita[h];
      float factor = 1.0f / (2.0f * ita * ita + 1e-6f);
      float bi = t1[idx * 8 + h] * t2[idx * 8 + h];
      float v = bi + 0.01f * expf(-factor * dv);
      comb[(size_t)h * TBL + idx] = v * L2E;
      combe[(size_t)h * TBL + idx] = expf(v);
    }
    return;
  }
  if (bid < 1024) {
    size_t base = ((size_t)bid * 256 + t) * 8;
    float v8[8];
    *(float4*)(v8) = *(const float4*)(x + base);
    *(float4*)(v8 + 4) = *(const float4*)(x + base + 4);
    short8 h8, l8;
    split8_pk(v8, h8, l8);
    *(short8*)(xh + base) = h8;
    *(short8*)(xl + base) = l8;
    return;
  }
  __shared__ float tile[64][65];
  const float* src;
  unsigned short *dh, *dl;
  int n0, k0, N;
  if (bid < 1216) {
    int b2 = bid - 1024;
    n0 = (b2 % 24) * 64; k0 = (b2 / 24) * 64; N = 1536;
    src = wqkv; dh = wth; dl = wtl;
  } else {
    int b2 = bid - 1216;
    n0 = (b2 % 8) * 64; k0 = (b2 / 8) * 64; N = 512;
    src = wout; dh = wouth; dl = woutl;
  }
#pragma unroll
  for (int l = 0; l < 4; ++l) {
    int idx = t + l * 256;
    int r = idx >> 4, c4 = idx & 15;
    float4 v = *(const float4*)(src + (size_t)(k0 + r) * N + n0 + c4 * 4);
    tile[r][c4 * 4 + 0] = v.x; tile[r][c4 * 4 + 1] = v.y;
    tile[r][c4 * 4 + 2] = v.z; tile[r][c4 * 4 + 3] = v.w;
  }
  __syncthreads();
#pragma unroll
  for (int l = 0; l < 2; ++l) {
    int idx = t + l * 256;
    int n = idx >> 3, c8 = idx & 7;
    float v8[8];
#pragma unroll
    for (int j = 0; j < 8; ++j) v8[j] = tile[c8 * 8 + j][n];
    short8 h8, l8;
    split8_pk(v8, h8, l8);
    *(short8*)(dh + (size_t)(n0 + n) * 512 + k0 + c8 * 8) = h8;
    *(short8*)(dl + (size_t)(n0 + n) * 512 + k0 + c8 * 8) = l8;
  }
}

// ---------------- shared MFMA GEMM core (split-bf16, AR x BR tile, K=512) ------
// A,B stored [row][512] bf16 row-major (hi/lo arrays). Stages ARx64 + BRx64
// tiles via global_load_lds, XOR-swizzled (16B unit u at row r -> u^(r&7)).
// 4 waves: wr = w>>1 owns M-half (AR/2), wc = w&1 owns N-half (BR/2).
// acc[mt][nt]: D[m = (AR/2)wr+16mt+4q+j][n = (BR/2)wc+16nt+li].
template <int AR, int BR>
__device__ __forceinline__ void gemm_core(
    const unsigned short* __restrict__ pAh, const unsigned short* __restrict__ pAl,
    const unsigned short* __restrict__ pBh, const unsigned short* __restrict__ pBl,
    int a0, int b0, int t, f32x4 acc[AR / 32][BR / 32],
    unsigned short* AhS, unsigned short* AlS,
    unsigned short* BhS, unsigned short* BlS) {
  constexpr int MT = AR / 32, NT = BR / 32;
  const int lane = t & 63;
  const int w = t >> 6;
  const int q = lane >> 4, li = lane & 15;
  const int wr = w >> 1, wc = w & 1;
#pragma unroll 1
  for (int k0 = 0; k0 < 512; k0 += 64) {
#pragma unroll
    for (int l = 0; l < AR / 32; ++l) {
      int idx = l * 256 + t;
      int row = idx >> 3, u = idx & 7;
      int so = k0 + ((u ^ (row & 7)) * 8);
      gload16(pAh + (size_t)(a0 + row) * 512 + so, AhS + idx * 8);
      gload16(pAl + (size_t)(a0 + row) * 512 + so, AlS + idx * 8);
    }
#pragma unroll
    for (int l = 0; l < BR / 32; ++l) {
      int idx = l * 256 + t;
      int row = idx >> 3, u = idx & 7;
      int so = k0 + ((u ^ (row & 7)) * 8);
      gload16(pBh + (size_t)(b0 + row) * 512 + so, BhS + idx * 8);
      gload16(pBl + (size_t)(b0 + row) * 512 + so, BlS + idx * 8);
    }
    __syncthreads();
#pragma unroll
    for (int c = 0; c < 2; ++c) {
      short8 aH[MT], aL[MT], bH[NT], bL[NT];
#pragma unroll
      for (int mt = 0; mt < MT; ++mt) {
        int row = (AR / 2) * wr + 16 * mt + li;
        int ro = row * 64 + (((4 * c + q) ^ (row & 7)) * 8);
        aH[mt] = *(const short8*)(AhS + ro);
        aL[mt] = *(const short8*)(AlS + ro);
      }
#pragma unroll
      for (int nt = 0; nt < NT; ++nt) {
        int row = (BR / 2) * wc + 16 * nt + li;
        int ro = row * 64 + (((4 * c + q) ^ (row & 7)) * 8);
        bH[nt] = *(const short8*)(BhS + ro);
        bL[nt] = *(const short8*)(BlS + ro);
      }
#pragma unroll
      for (int mt = 0; mt < MT; ++mt)
#pragma unroll
        for (int nt = 0; nt < NT; ++nt) {
          acc[mt][nt] = mfma16(aH[mt], bH[nt], acc[mt][nt]);
          acc[mt][nt] = mfma16(aH[mt], bL[nt], acc[mt][nt]);
          acc[mt][nt] = mfma16(aL[mt], bH[nt], acc[mt][nt]);
        }
    }
    __syncthreads();
  }
}

// ---------------- Kernel 1: QKV GEMM — 768 blocks (3/CU), 64x128 tiles ---------
// bx = part*8 + h (24), by = 128-token tile (32). Q/K swapped (A=W^T 64 rows,
// B=x 128 rows): lane holds 4 consecutive d. V normal (A=x, B=W^T): lane holds
// 4 consecutive tokens for one d.
__global__ __launch_bounds__(256, 3) void k_qkv(
    const unsigned short* __restrict__ xh, const unsigned short* __restrict__ xl,
    const unsigned short* __restrict__ wth, const unsigned short* __restrict__ wtl,
    float* __restrict__ qf, unsigned short* __restrict__ kspl,
    unsigned short* __restrict__ vspl) {
  __shared__ unsigned short S[24576];  // 48 KB
  const int bid = blockIdx.x;                 // 0..767
  const int lin = (bid & 7) * 96 + (bid >> 3);
  const int by = lin / 24, bx = lin % 24;
  const int part = bx >> 3, h = bx & 7;
  const int t = threadIdx.x;
  const int lane = t & 63;
  const int w = t >> 6;
  const int q = lane >> 4, li = lane & 15;
  const int wr = w >> 1, wc = w & 1;

  if (part < 2) {
    f32x4 acc[2][4] = {};
    int a0 = part * 512 + h * 64;
    gemm_core<64, 128>(wth, wtl, xh, xl, a0, by * 128, t, acc,
                       S, S + 4096, S + 8192, S + 16384);
    if (part == 0) {
#pragma unroll
      for (int nt = 0; nt < 4; ++nt) {
        int tok = by * 128 + 64 * wc + 16 * nt + li;
        int b = tok >> 10, i = tok & 1023;
#pragma unroll
        for (int mt = 0; mt < 2; ++mt) {
          int d0 = 32 * wr + 16 * mt + 4 * q;
          float4 v;
          v.x = acc[mt][nt][0]; v.y = acc[mt][nt][1];
          v.z = acc[mt][nt][2]; v.w = acc[mt][nt][3];
          *(float4*)(qf + ((size_t)(b * NH + h) * NTOK + i) * DH + d0) = v;
        }
      }
    } else {
#pragma unroll
      for (int nt = 0; nt < 4; ++nt) {
        int tok = by * 128 + 64 * wc + 16 * nt + li;
        int b = tok >> 10, tile = (tok & 1023) >> 6, tl = tok & 63;
        unsigned short* kb = kspl + ((size_t)((b * NH + h) * 16 + tile) * 2) * 4096;
#pragma unroll
        for (int mt = 0; mt < 2; ++mt) {
          int d0 = 32 * wr + 16 * mt + 4 * q;
          int pu = (d0 >> 3) ^ (tl & 7), off = d0 & 7;
          unsigned h0, h1, l0, l1;
          cvt2(acc[mt][nt][0], acc[mt][nt][1], h0, l0);
          cvt2(acc[mt][nt][2], acc[mt][nt][3], h1, l1);
          *(uint2*)(kb + tl * 64 + pu * 8 + off) = make_uint2(h0, h1);
          *(uint2*)(kb + 4096 + tl * 64 + pu * 8 + off) = make_uint2(l0, l1);
        }
      }
    }
  } else {
    f32x4 acc[4][2] = {};
    gemm_core<128, 64>(xh, xl, wth, wtl, by * 128, 1024 + h * 64, t, acc,
                       S, S + 8192, S + 16384, S + 20480);
#pragma unroll
    for (int mt = 0; mt < 4; ++mt) {
      int tok0 = by * 128 + 64 * wr + 16 * mt + 4 * q;
      int b = tok0 >> 10, tile = (tok0 & 1023) >> 6, tl0 = tok0 & 63;
      int lu = tl0 >> 3, off = tl0 & 7;
      unsigned short* vb = vspl + ((size_t)((b * NH + h) * 16 + tile) * 2) * 4096;
#pragma unroll
      for (int nt = 0; nt < 2; ++nt) {
        int d = 32 * wc + 16 * nt + li;
        int pu = lu ^ (d & 7);
        unsigned h0, h1, l0, l1;
        cvt2(acc[mt][nt][0], acc[mt][nt][1], h0, l0);
        cvt2(acc[mt][nt][2], acc[mt][nt][3], h1, l1);
        *(uint2*)(vb + d * 64 + pu * 8 + off) = make_uint2(h0, h1);
        *(uint2*)(vb + 4096 + d * 64 + pu * 8 + off) = make_uint2(l0, l1);
      }
    }
  }
}

// ---------------- Kernel 2: fused attention, 8 waves, XCD-swizzled -------------
// attn0 emitted with direct PLAIN dword stores (L2 write-back merges 64B
// quarter-wave granules; NT scatter measured +45-57 MB HBM amplification,
// LDS-staged bulk copy measured +7 µs overhead).
// __launch_bounds__(512,4): 60 VGPR, no spill. (512,6) measured: VGPR forced
// to 40 -> ~250 MB scratch spill traffic, dur 102 -> 162 µs. Do not re-try.
__global__ __launch_bounds__(512, 4) void k_attn(
    const float* __restrict__ qf, const unsigned short* __restrict__ kspl,
    const unsigned short* __restrict__ vspl, const float* __restrict__ prob,
    const float* __restrict__ comb, const float* __restrict__ combe,
    const float* __restrict__ wt,
    float* __restrict__ attn0, unsigned short* __restrict__ oh,
    unsigned short* __restrict__ ol) {
  __shared__ unsigned short KhS[4096], KlS[4096];  // K [tok][d] bf16 hi/lo (swz)
  __shared__ unsigned short VhS[4096], VlS[4096];  // V^T [d][jj] bf16 hi/lo (swz)
  __shared__ float PfS[64 * 68];                   // P / merge scratch
  __shared__ float2 csS[3 * 64];                   // (comb*log2e, exp(comb))
  __shared__ float thrS[64];

  const int bid = blockIdx.x;
  const int lin = (bid & 7) * 64 + (bid >> 3);  // 16 row-tiles of a bh per XCD
  const int bh = lin >> 4;
  const int rt = lin & 15;
  const int b = bh >> 3, h = bh & 7;
  const int i0 = rt * 64;
  const int t = threadIdx.x;
  const int w = t >> 6;
  const int lane = t & 63;
  const int q = lane >> 4, li = lane & 15;
  const int g = w >> 1;                    // rows 16g..16g+15
  const int cw = w & 1;                    // column half
  const float* qb = qf + (size_t)bh * NTOK * DH;
  const float* ch = comb + (size_t)h * TBL;
  const float* che = combe + (size_t)h * TBL;
  const int rbase = (i0 >> 5) + 30;

  // thresh_raw = sigmoid(q . W_thresh) * sigmoid(-2)
  {
    int row = t >> 3, dg = t & 7;
    const float* qr2 = qb + (size_t)(i0 + row) * DH + dg * 8;
    float sum = 0.f;
#pragma unroll
    for (int c = 0; c < 8; ++c) sum += qr2[c] * wt[dg * 8 + c];
    sum += __shfl_xor(sum, 1);
    sum += __shfl_xor(sum, 2);
    sum += __shfl_xor(sum, 4);
    if (dg == 0)
      thrS[row] = (1.0f / (1.0f + exp2f(-sum * L2E))) * 0.11920292202211755f;
  }

  // Q fragments, prescaled by 0.125*log2e
  short8 qah[2], qal[2];
  {
    const float* qr2 = qb + (size_t)(i0 + 16 * g + li) * DH;
    const float QS = 0.125f * L2E;
#pragma unroll
    for (int c = 0; c < 2; ++c) {
      float4 a = *(const float4*)(qr2 + 32 * c + 8 * q);
      float4 bb = *(const float4*)(qr2 + 32 * c + 8 * q + 4);
      float tmp[8] = {a.x * QS, a.y * QS, a.z * QS, a.w * QS,
                      bb.x * QS, bb.y * QS, bb.z * QS, bb.w * QS};
      split8_pk(tmp, qah[c], qal[c]);
    }
  }

  float m0l[4], s0l[4], ml[4], sl[4], mnl[4];
#pragma unroll
  for (int r = 0; r < 4; ++r) {
    m0l[r] = -1e30f; ml[r] = -1e30f; mnl[r] = 1e30f;
    s0l[r] = 0.f; sl[r] = 0.f;
  }

  // ================= pass 1: stats =================
#pragma unroll 1
  for (int j0 = 0; j0 < NTOK; j0 += 64) {
    const unsigned short* gk = kspl + ((size_t)(bh * 16 + (j0 >> 6)) * 2) * 4096;
    gload16(gk + w * 512 + lane * 8, KhS + w * 512);
    gload16(gk + 4096 + w * 512 + lane * 8, KlS + w * 512);
    if (t < 192) {
      int rl2 = t >> 6, c2 = t & 63;
      if (c2 < 63) {
        int off = (rbase - (j0 >> 5) + rl2) * 63 + c2;
        csS[rl2 * 64 + c2] = make_float2(ch[off], che[off]);
      }
    }
    __syncthreads();

    f32x4 acc2[2] = {};
#pragma unroll
    for (int c = 0; c < 2; ++c) {
#pragma unroll
      for (int T2 = 0; T2 < 2; ++T2) {
        int T = 2 * cw + T2;
        int ro = (16 * T + li) * 64 + ((4 * c + q) ^ (li & 7)) * 8;
        short8 bh8 = *(const short8*)(KhS + ro);
        short8 bl8 = *(const short8*)(KlS + ro);
        acc2[T2] = mfma16(qah[c], bh8, acc2[T2]);
        acc2[T2] = mfma16(qah[c], bl8, acc2[T2]);
        acc2[T2] = mfma16(qal[c], bh8, acc2[T2]);
      }
    }

    float2 ce[2][4];
    float t0[4], tt[4], tmn[4];
#pragma unroll
    for (int r = 0; r < 4; ++r) { t0[r] = -1e30f; tt[r] = -1e30f; tmn[r] = 1e30f; }
#pragma unroll
    for (int T2 = 0; T2 < 2; ++T2) {
      int jj = 16 * (2 * cw + T2) + li;
      int rl2 = (g >> 1) - (jj >> 5) + 1;
      int cb = 16 * (g & 1) + 4 * q - (jj & 31) + 31;
      const float2* cp = csS + rl2 * 64 + cb;
#pragma unroll
      for (int r = 0; r < 4; ++r) {
        ce[T2][r] = cp[r];
        float d0 = acc2[T2][r];
        float dt = d0 + ce[T2][r].x;
        t0[r] = fmaxf(t0[r], d0);
        tt[r] = fmaxf(tt[r], dt);
        tmn[r] = fminf(tmn[r], dt);
      }
    }
#pragma unroll
    for (int r = 0; r < 4; ++r) {
      float nm0 = fmaxf(m0l[r], t0[r]);
      float nm = fmaxf(ml[r], tt[r]);
      float sc0 = exp2f(m0l[r] - nm0), sc = exp2f(ml[r] - nm), k0 = exp2f(nm0 - nm);
      float s0a = 0.f, sEa = 0.f;
#pragma unroll
      for (int T2 = 0; T2 < 2; ++T2) {
        float e0 = exp2f(acc2[T2][r] - nm0);
        s0a += e0;
        sEa += e0 * ce[T2][r].y;
      }
      s0l[r] = s0l[r] * sc0 + s0a;
      sl[r] = sl[r] * sc + sEa * k0;
      m0l[r] = nm0; ml[r] = nm; mnl[r] = fminf(mnl[r], tmn[r]);
    }
    __syncthreads();
  }

  // ========= finalize: intra-wave (li) reduce, cross-pair merge via LDS =======
  float M0[4], S0v[4], M[4], Sv[4], MN[4];
#pragma unroll
  for (int r = 0; r < 4; ++r) {
    float m0v = m0l[r], s0 = s0l[r], m = ml[r], s = sl[r], mn = mnl[r];
#pragma unroll
    for (int off = 1; off < 16; off <<= 1) {
      float om = __shfl_xor(m0v, off), os = __shfl_xor(s0, off);
      float n0 = fmaxf(m0v, om);
      s0 = s0 * exp2f(m0v - n0) + os * exp2f(om - n0);
      m0v = n0;
      float om2 = __shfl_xor(m, off), os2 = __shfl_xor(s, off);
      float n2 = fmaxf(m, om2);
      s = s * exp2f(m - n2) + os2 * exp2f(om2 - n2);
      m = n2;
      mn = fminf(mn, __shfl_xor(mn, off));
    }
    M0[r] = m0v; S0v[r] = s0; M[r] = m; Sv[r] = s; MN[r] = mn;
  }
  if (li == 0) {
#pragma unroll
    for (int r = 0; r < 4; ++r) {
      int row = 16 * g + 4 * q + r;
      float* p = PfS + (cw * 64 + row) * 5;
      p[0] = M0[r]; p[1] = S0v[r]; p[2] = M[r]; p[3] = Sv[r]; p[4] = MN[r];
    }
  }
  __syncthreads();

  float m0f[4], is0f[4], thf[4], crf[4];
#pragma unroll
  for (int r = 0; r < 4; ++r) {
    int rloc = 16 * g + 4 * q + r;
    const float* pa = PfS + rloc * 5;
    const float* pb = PfS + (64 + rloc) * 5;
    float m0v = fmaxf(pa[0], pb[0]);
    float s0 = pa[1] * exp2f(pa[0] - m0v) + pb[1] * exp2f(pb[0] - m0v);
    float m = fmaxf(pa[2], pb[2]);
    float s = pa[3] * exp2f(pa[2] - m) + pb[3] * exp2f(pb[2] - m);
    float mn = fminf(pa[4], pb[4]);
    float isf = 1.f / s;
    float amin = exp2f(mn - m) * isf;
    float th = amin + thrS[rloc] * (isf - amin);
    if (prob[b * NTOK + i0 + rloc] >= 0.9f) th = 1e30f;
    m0f[r] = m0v; is0f[r] = 1.f / s0; thf[r] = th; crf[r] = exp2f(m0v - m) * isf;
  }
  __syncthreads();  // scratch reads done before pass 2 overwrites PfS

  // ================= pass 2: attn0 (direct plain stores), P, PV =================
  f32x4 oacc[4] = {};
  float denl[4] = {0.f, 0.f, 0.f, 0.f};
#pragma unroll 1
  for (int j0 = 0; j0 < NTOK; j0 += 64) {
    const unsigned short* gk = kspl + ((size_t)(bh * 16 + (j0 >> 6)) * 2) * 4096;
    const unsigned short* gv = vspl + ((size_t)(bh * 16 + (j0 >> 6)) * 2) * 4096;
    gload16(gk + w * 512 + lane * 8, KhS + w * 512);
    gload16(gk + 4096 + w * 512 + lane * 8, KlS + w * 512);
    gload16(gv + w * 512 + lane * 8, VhS + w * 512);
    gload16(gv + 4096 + w * 512 + lane * 8, VlS + w * 512);
    if (t < 192) {
      int rl2 = t >> 6, c2 = t & 63;
      if (c2 < 63) {
        int off = (rbase - (j0 >> 5) + rl2) * 63 + c2;
        csS[rl2 * 64 + c2] = make_float2(ch[off], che[off]);
      }
    }
    __syncthreads();

    f32x4 acc2[2] = {};
#pragma unroll
    for (int c = 0; c < 2; ++c) {
#pragma unroll
      for (int T2 = 0; T2 < 2; ++T2) {
        int T = 2 * cw + T2;
        int ro = (16 * T + li) * 64 + ((4 * c + q) ^ (li & 7)) * 8;
        short8 bh8 = *(const short8*)(KhS + ro);
        short8 bl8 = *(const short8*)(KlS + ro);
        acc2[T2] = mfma16(qah[c], bh8, acc2[T2]);
        acc2[T2] = mfma16(qah[c], bl8, acc2[T2]);
        acc2[T2] = mfma16(qal[c], bh8, acc2[T2]);
      }
    }

#pragma unroll
    for (int T2 = 0; T2 < 2; ++T2) {
      int jj = 16 * (2 * cw + T2) + li;
      int rl2 = (g >> 1) - (jj >> 5) + 1;
      int cb = 16 * (g & 1) + 4 * q - (jj & 31) + 31;
      const float2* cp = csS + rl2 * 64 + cb;
      int il0 = 16 * g + 4 * q;
      float* a0p = attn0 + (size_t)(bh * NTOK + i0 + il0) * NTOK + j0 + jj;
#pragma unroll
      for (int r = 0; r < 4; ++r) {
        float ey = cp[r].y;
        float e0 = exp2f(acc2[T2][r] - m0f[r]);
        a0p[(size_t)r * NTOK] = e0 * is0f[r];   // plain store: L2 merges lines
        float at = e0 * ey * crf[r];
        float p = (at - thf[r] > 0.f) ? at : 0.f;
        denl[r] += p;
        PfS[(il0 + r) * 68 + jj] = p;
      }
    }
    // PV over this wave's 32 j-cols (wave-private P region), all 64 d
    {
      const float* pp = PfS + (16 * g + li) * 68 + 32 * cw + 8 * q;
      float pv8[8];
      *(float4*)(pv8) = *(const float4*)pp;
      *(float4*)(pv8 + 4) = *(const float4*)(pp + 4);
      short8 pah, pal;
      split8_pk(pv8, pah, pal);
#pragma unroll
      for (int T = 0; T < 4; ++T) {
        int ro = (16 * T + li) * 64 + ((4 * cw + q) ^ (li & 7)) * 8;
        short8 vh8 = *(const short8*)(VhS + ro);
        short8 vl8 = *(const short8*)(VlS + ro);
        oacc[T] = mfma16(pah, vh8, oacc[T]);
        oacc[T] = mfma16(pah, vl8, oacc[T]);
        oacc[T] = mfma16(pal, vh8, oacc[T]);
      }
    }
    __syncthreads();
  }

  // ========= epilogue: merge O + deno across wave pair, store split-bf16 ======
#pragma unroll
  for (int r = 0; r < 4; ++r) {
#pragma unroll
    for (int off = 1; off < 16; off <<= 1) denl[r] += __shfl_xor(denl[r], off);
  }
  if (cw == 1) {
#pragma unroll
    for (int r = 0; r < 4; ++r) {
      int row = 16 * g + 4 * q + r;
#pragma unroll
      for (int T = 0; T < 4; ++T) PfS[row * 68 + 16 * T + li] = oacc[T][r];
      if (li == 0) PfS[row * 68 + 64] = denl[r];
    }
  }
  __syncthreads();
  if (cw == 0) {
#pragma unroll
    for (int r = 0; r < 4; ++r) {
      int rloc = 16 * g + 4 * q + r;
      float dsum = denl[r] + PfS[rloc * 68 + 64];
      float pf = 1.f / (dsum + 1e-6f);
      int row = i0 + rloc;
      size_t rb2 = ((size_t)b * NTOK + row) * 512 + h * 64;
#pragma unroll
      for (int T = 0; T < 4; ++T) {
        float val = (oacc[T][r] + PfS[rloc * 68 + 16 * T + li]) * pf;
        unsigned hv = bf16rne(val);
        float lo2 = val - __uint_as_float(hv << 16);
        oh[rb2 + 16 * T + li] = (unsigned short)hv;
        ol[rb2 + 16 * T + li] = (unsigned short)bf16rne(lo2);
      }
    }
  }
}

// ---------------- Kernel 3: output GEMM — 256 blocks (1/CU), 64x128 tiles ------
__global__ __launch_bounds__(256, 3) void k_out(
    const unsigned short* __restrict__ wouth, const unsigned short* __restrict__ woutl,
    const unsigned short* __restrict__ oh, const unsigned short* __restrict__ ol,
    const float* __restrict__ bias, float* __restrict__ c) {
  __shared__ unsigned short S[24576];
  const int bid = blockIdx.x;                 // 0..255
  const int lin = (bid & 7) * 32 + (bid >> 3);
  const int by = lin >> 3, bx = lin & 7;
  const int t = threadIdx.x;
  const int lane = t & 63;
  const int w = t >> 6;
  const int q = lane >> 4, li = lane & 15;
  const int wr = w >> 1, wc = w & 1;
  f32x4 acc[2][4] = {};
  gemm_core<64, 128>(wouth, woutl, oh, ol, bx * 64, by * 128, t, acc,
                     S, S + 4096, S + 8192, S + 16384);
#pragma unroll
  for (int mt = 0; mt < 2; ++mt) {
    int col0 = bx * 64 + 32 * wr + 16 * mt + 4 * q;
    float4 b4 = *(const float4*)(bias + col0);
#pragma unroll
    for (int nt = 0; nt < 4; ++nt) {
      int tok = by * 128 + 64 * wc + 16 * nt + li;
      float4 v;
      v.x = acc[mt][nt][0] + b4.x; v.y = acc[mt][nt][1] + b4.y;
      v.z = acc[mt][nt][2] + b4.z; v.w = acc[mt][nt][3] + b4.w;
      *(float4*)(c + (size_t)tok * 512 + col0) = v;
    }
  }
}

extern "C" void kernel_launch(void* const* d_in, const int* in_sizes, int n_in,
                              void* d_out, int out_size, void* d_ws, size_t ws_size,
                              hipStream_t stream) {
  const float* x    = (const float*)d_in[0];
  const float* prob = (const float*)d_in[1];
  const float* wqkv = (const float*)d_in[2];
  const float* t1   = (const float*)d_in[3];
  const float* t2   = (const float*)d_in[4];
  const float* sita = (const float*)d_in[5];
  const float* wt   = (const float*)d_in[6];
  const float* wout = (const float*)d_in[7];
  const float* bout = (const float*)d_in[8];
  const float* dis  = (const float*)d_in[10];

  float* out = (float*)d_out;
  float* attn0 = out + (size_t)BATCH * NTOK * 512;

  float* comb = (float*)d_ws;                          // 32768 f (log2 domain)
  float* combe = comb + 32768;                         // 32768 f
  float* qf = combe + 32768;                           // 2,097,152 f (Q fp32)
  unsigned short* kspl = (unsigned short*)(qf + (size_t)BATCH * NH * NTOK * DH);  // 8 MB
  unsigned short* vspl = kspl + (size_t)4194304;                                  // 8 MB
  unsigned short* xh = vspl + (size_t)4194304;         // 4 MB (reused as oh)
  unsigned short* xl = xh + (size_t)2097152;           // 4 MB (reused as ol)
  unsigned short* wth = xl + (size_t)2097152;          // 1.5 MB
  unsigned short* wtl = wth + (size_t)786432;          // 1.5 MB
  unsigned short* wouth = wtl + (size_t)786432;        // 0.5 MB
  unsigned short* woutl = wouth + (size_t)262144;      // 0.5 MB
  unsigned short* oh = xh;  // alias: x consumed by k_qkv before k_attn writes o
  unsigned short* ol = xl;

  hipLaunchKernelGGL(k_prep, dim3(1296), dim3(256), 0, stream,
                     x, wqkv, wout, xh, xl, wth, wtl, wouth, woutl,
                     t1, t2, sita, dis, comb, combe);
  hipLaunchKernelGGL(k_qkv, dim3(768), dim3(256), 0, stream,
                     xh, xl, wth, wtl, qf, kspl, vspl);
  hipLaunchKernelGGL(k_attn, dim3(512), dim3(512), 0, stream,
                     qf, kspl, vspl, prob, comb, combe, wt, attn0, oh, ol);
  hipLaunchKernelGGL(k_out, dim3(256), dim3(256), 0, stream,
                     wouth, woutl, oh, ol, bout, out);
}